// Round 16
// baseline (227.696 us; speedup 1.0000x reference)
//
#include <hip/hip_runtime.h>

// Problem: VOCAB=10000, EMB=100, T=80, UNITS=256, BATCH=4096 — ALL FP32 I/O.
// out = sigmoid(h2_T);  h_l,t = tanh(x_l,t @ Wl + h_l,t-1 @ Ul + bl)
//
// v21 theory (from v20 counters): corrected per-SIMD MFMA cost (19.4cy/mfma
// per SIMD, 4 SIMDs share the 2075TF ceiling) => iter 4180cy ~= MFMA 1860 +
// VALU 1960 run SEQUENTIALLY: both waves/SIMD are barrier-locked into the
// same phase (all-MFMA then all-tanh) — also why setprio was null (no role
// diversity). Fix: WAVE ROLE SPLIT. G0 (waves 0-3) = layer-1 only (4 tiles,
// 32 MFMA + 16 tanh); G1 (waves 4-7) = layer-2 only (4 tiles, 64 MFMA +
// 16 tanh). Wave i -> SIMD i%4 => one G0 + one G1 per SIMD: G0's tanh runs
// UNDER G1's longer MFMA phase; only G1's tail tanh stays exposed.
// Est 2700cy/iter vs 4180. Registers DROP: G0 pins U1(128)~170 live;
// G1 pins W2(128) + streams ALL U2 from 128KB LDS (static 32K + dyn 128K
// = 160KB max) ~190 live — both under the spill law. Same dep structure:
// iter i: G0->h1[i], G1->h2[i-1]; one lgkm-only barrier; swapped-operand
// MFMA; P1 2xb64 register gather (G0), prefetched one iter ahead.
// Tripwire: WRITE_SIZE must stay 4.1 MB.
#define BATCH 4096
#define TLEN  80
#define EMBD  100
#define UNITS 256

typedef _Float16 f16;
typedef __attribute__((ext_vector_type(8))) _Float16 h8;   // 8 f16 = 4 VGPR MFMA A/B frag
typedef __attribute__((ext_vector_type(4))) _Float16 h4;   // 4 f16 = b64
typedef __attribute__((ext_vector_type(4))) float f32x4;   // MFMA C/D frag

// tanh(x) = sign(x) * (1-e)/(1+e), e = exp(-2|x|) in (0,1].
__device__ __forceinline__ float fast_tanh(float x) {
  float ax = __builtin_fabsf(x);
  float e  = __expf(-2.f * ax);
  float r  = (1.f - e) * __builtin_amdgcn_rcpf(1.f + e);
  return __builtin_copysignf(r, x);
}
// sigmoid(x) = rcp(1 + exp(-x)); saturates correctly at both ends.
__device__ __forceinline__ float fast_sigmoid(float x) {
  return __builtin_amdgcn_rcpf(1.f + __expf(-x));
}

// LDS-only barrier: all prior LDS ops visible, but vmcnt NOT drained.
__device__ __forceinline__ void block_sync_lds() {
  asm volatile("s_waitcnt lgkmcnt(0)\n\ts_barrier" ::: "memory");
}

// ---------------- workspace layout (5.58 MB <= 6.04 MB proven available) ---
// P1 table: 10000 x 256 f16 = 5,120,000 B.  wf frags: 458,752 B.
// B-frag layout (16x16x32, r7-verified): lane holds B[k=quad*8+j][n=lane&15].
// ktg slots: W1 = 0..3 (unused by main), U1 = 4..11, W2 = 12..19, U2 = 20..27.
#define KT_ALL 28
#define OFF_P1 ((size_t)0)
#define P1_BYTES ((size_t)10000 * UNITS * 2)                // 5,120,000
#define OFF_WF  P1_BYTES
#define WF_BYTES ((size_t)KT_ALL * 16 * 64 * 8 * 2)         //   458,752
#define WS_NEED (OFF_WF + WF_BYTES)                          // 5,578,752 B

__device__ __forceinline__ size_t fidx(int ktg, int nt, int lane) {
  return (((size_t)ktg * 16 + nt) * 64 + lane) * 8;
}

// ---------------- precompute: weights -> swizzled fp16 B-frags (r10-verified)
__global__ __launch_bounds__(256) void k_split_w16(
    const float* __restrict__ W1, const float* __restrict__ U1,
    const float* __restrict__ W2, const float* __restrict__ U2,
    f16* __restrict__ wf)
{
  int gid = blockIdx.x * 256 + threadIdx.x;           // one per (ktg,nt,lane)
  if (gid >= KT_ALL * 16 * 64) return;
  int lane = gid & 63, nt = (gid >> 6) & 15, ktg = gid >> 10;
  const float* M; int Kact, ktl;
  if (ktg < 4)       { M = W1; Kact = EMBD;  ktl = ktg;      }
  else if (ktg < 12) { M = U1; Kact = UNITS; ktl = ktg - 4;  }
  else if (ktg < 20) { M = W2; Kact = UNITS; ktl = ktg - 12; }
  else               { M = U2; Kact = UNITS; ktl = ktg - 20; }
  int n = nt * 16 + (lane & 15);
  int kb = ktl * 32 + (lane >> 4) * 8;
  size_t base = fidx(ktg, nt, lane);
#pragma unroll
  for (int j = 0; j < 8; ++j) {
    int k = kb + j;
    wf[base + j] = (f16)((k < Kact) ? M[(size_t)k * UNITS + n] : 0.f);  // RNE
  }
}

// ---------------- precompute: P1[v][n] = b1[n] + emb[v,:] @ W1 (f32 math) --
__global__ __launch_bounds__(256) void k_p1(
    const float* __restrict__ emb, const float* __restrict__ W1,
    const float* __restrict__ b1, f16* __restrict__ p1t)
{
  __shared__ float er[16][EMBD];
  const int v0 = blockIdx.x * 16;
  for (int i = threadIdx.x; i < 16 * EMBD; i += 256) {
    int vv = i / EMBD, kk = i - vv * EMBD;
    er[vv][kk] = emb[(size_t)(v0 + vv) * EMBD + kk];
  }
  __syncthreads();
  const int n = threadIdx.x;
  float acc[16];
  const float bb = b1[n];
#pragma unroll
  for (int vv = 0; vv < 16; ++vv) acc[vv] = bb;
  for (int k = 0; k < EMBD; ++k) {
    float w = W1[(size_t)k * UNITS + n];
#pragma unroll
    for (int vv = 0; vv < 16; ++vv) acc[vv] += er[vv][k] * w;
  }
#pragma unroll
  for (int vv = 0; vv < 16; ++vv)
    p1t[(size_t)(v0 + vv) * UNITS + n] = (f16)acc[vv];
}

#define MFMA16(A, B, C) __builtin_amdgcn_mfma_f32_16x16x32_f16(A, B, C, 0, 0, 0)

// store 4 consecutive-n f16 of the next-step A-frag in ONE b64 write.
// A-frag element (batch=m, k=n) lives at (n>>5)*512 + (((n>>3)&3)*16+m)*8
// + (n&7); for nb multiple of 4, the 4 targets are consecutive (8B-aligned).
__device__ __forceinline__ void store_row4(f16* __restrict__ f, int nb, int m,
                                           float v0, float v1, float v2, float v3) {
  int a = (nb >> 5) * 512 + (((nb >> 3) & 3) * 16 + m) * 8 + (nb & 7);
  h4 p; p[0] = (f16)v0; p[1] = (f16)v1; p[2] = (f16)v2; p[3] = (f16)v3;
  *(h4*)&f[a] = p;
}

// ---------------------------------------------------------------------------
// Main kernel v21: 512 thr = 8 waves; wave i -> SIMD i%4.
// G0 = waves 0-3: layer-1, tiles 4wt..4wt+3, pins U1 (128 regs).
// G1 = waves 4-7: layer-2, tiles 4wt..4wt+3, pins W2 (128 regs), streams U2
// from 128 KB LDS. SWAPPED-OPERAND MFMA: lane holds (4 consecutive n, row m).
// Iter i: G0 -> h1[i] (32 MFMA + 16 tanh), G1 -> h2[i-1] (64 MFMA + 16 tanh);
// one lgkm-only barrier/iter; compile-time buffer indices.
// ---------------------------------------------------------------------------
__global__ __launch_bounds__(512, 2)
__attribute__((amdgpu_waves_per_eu(2, 2)))
void rnn_wsH(
    const int* __restrict__ idx, const f16* __restrict__ p1t,
    const f16* __restrict__ wf, const float* __restrict__ b2,
    float* __restrict__ out)
{
  __shared__ __align__(16) f16 f1[2][4096];      // [buf][kt*512 + lane*8 + j]
  __shared__ __align__(16) f16 f2[2][4096];
  extern __shared__ f16 u2s[];                   // 128 KB: ALL 16 U2 tiles
                                                 // [(t*8+kt)*64+lane]*8

  const int tid  = threadIdx.x;
  const int lane = tid & 63;
  const int w    = tid >> 6;
  const bool g0  = (w < 4);           // waves 0-3 = G0 (L1), 4-7 = G1 (L2)
  const int wt   = g0 ? w : w - 4;    // group-local wave id: tiles 4wt..4wt+3
  const int m    = lane & 15;         // batch row this lane accumulates
  const int q    = lane >> 4;
  const int b0   = blockIdx.x * 16;

  int nb[4];                          // 4-col group bases of the 4 owned tiles
#pragma unroll
  for (int j = 0; j < 4; ++j) nb[j] = 64 * wt + 16 * j + 4 * q;

  // -------- stage ALL U2 tiles into LDS (128 KB / 512 thr = 16 h8 each) ---
  for (int d = tid; d < 8192; d += 512) {        // d = (t*8+kt)*64 + l
    int l = d & 63, g = d >> 6, t = g >> 3, kt = g & 7;
    *(h8*)&u2s[(size_t)d * 8] = *(const h8*)(wf + fidx(20 + kt, t, l));
  }

  // -------- pinned weights: G0 = U1 tiles, G1 = W2 tiles (128 regs) --------
  h8 Bp[4][8];
  {
    const int ktg0 = g0 ? 4 : 12;
#pragma unroll
    for (int j = 0; j < 4; ++j)
#pragma unroll
      for (int kt = 0; kt < 8; ++kt)
        Bp[j][kt] = *(const h8*)(wf + fidx(ktg0 + kt, 4 * wt + j, lane));
  }
#pragma unroll
  for (int j = 0; j < 4; ++j)
#pragma unroll
    for (int kt = 0; kt < 8; ++kt)
      asm volatile("" : "+v"(Bp[j][kt]));

  // -------- G1: bias vectors; G0: token/P1 pipeline ------------------------
  f32x4 b2v[4];
  if (!g0) {
#pragma unroll
    for (int j = 0; j < 4; ++j) b2v[j] = *(const f32x4*)&b2[nb[j]];
  }
  const int* tokm = idx + (size_t)(b0 + m) * TLEN;

  // -------- zero h2[-1] state (f2[0]); f1[0] fully written by the peel -----
  for (int i = tid; i < 4096; i += 512) f2[0][i] = (f16)0.f;

  // -------- peel i=0 (G0): h1[0] = tanh(P1[0]); prime P1 pipeline ----------
  h4 pv[4];
  int tkn = 0;
  if (g0) {
    const f16* pr = p1t + (size_t)tokm[0] * UNITS;
#pragma unroll
    for (int j = 0; j < 4; ++j) {
      h4 v = *(const h4*)(pr + nb[j]);
      store_row4(f1[0], nb[j], m, fast_tanh((float)v[0]), fast_tanh((float)v[1]),
                                  fast_tanh((float)v[2]), fast_tanh((float)v[3]));
    }
    const f16* pr1 = p1t + (size_t)tokm[1] * UNITS;
#pragma unroll
    for (int j = 0; j < 4; ++j) pv[j] = *(const h4*)(pr1 + nb[j]);
    tkn = tokm[2];
  }
  __syncthreads();   // full barrier once: u2s, f2 zero, peel

  // ======== one pipelined step; RD/WR are COMPILE-TIME 0/1 =================
  // G0: h1[i] = tanh(P1[i] + h1[i-1]@U1)  — reads f1[RD], writes f1[WR].
  // G1: h2[i-1] = tanh(b2 + h1[i-1]@W2 + h2[i-2]@U2) — reads f1[RD], f2[RD],
  //     writes f2[WR].  One lgkm-only barrier.
#define RNN_STEP(RD, WR, STAGE, TKI)                                         \
  {                                                                          \
    if (g0) {                                                                \
      f32x4 x[4];                                                            \
      _Pragma("unroll")                                                      \
      for (int j = 0; j < 4; ++j)                                            \
        _Pragma("unroll")                                                    \
        for (int r = 0; r < 4; ++r) x[j][r] = (float)pv[j][r];               \
      if (STAGE) {                                                           \
        const f16* pr_ = p1t + (size_t)tkn * UNITS;                          \
        _Pragma("unroll")                                                    \
        for (int j = 0; j < 4; ++j) pv[j] = *(const h4*)(pr_ + nb[j]);       \
      }                                                                      \
      tkn = tokm[TKI];                                                       \
      _Pragma("unroll")                                                      \
      for (int kt = 0; kt < 8; ++kt) {                                       \
        h8 a1 = *(const h8*)&f1[RD][kt * 512 + lane * 8];                    \
        _Pragma("unroll")                                                    \
        for (int j = 0; j < 4; ++j) x[j] = MFMA16(Bp[j][kt], a1, x[j]);      \
      }                                                                      \
      _Pragma("unroll")                                                      \
      for (int j = 0; j < 4; ++j)                                            \
        store_row4(f1[WR], nb[j], m, fast_tanh(x[j][0]), fast_tanh(x[j][1]), \
                                     fast_tanh(x[j][2]), fast_tanh(x[j][3]));\
    } else {                                                                 \
      f32x4 yA[4], yB[4];                                                    \
      _Pragma("unroll")                                                      \
      for (int j = 0; j < 4; ++j) {                                          \
        yA[j] = b2v[j];                                                      \
        yB[j] = (f32x4){0.f, 0.f, 0.f, 0.f};                                 \
      }                                                                      \
      _Pragma("unroll")                                                      \
      for (int kt = 0; kt < 8; ++kt) {                                       \
        h8 a1 = *(const h8*)&f1[RD][kt * 512 + lane * 8];                    \
        h8 a2 = *(const h8*)&f2[RD][kt * 512 + lane * 8];                    \
        _Pragma("unroll")                                                    \
        for (int j = 0; j < 4; ++j) {                                        \
          h8 ub = *(const h8*)&u2s[(((4 * wt + j) * 8 + kt) * 64 + lane) * 8];\
          yA[j] = MFMA16(Bp[j][kt], a1, yA[j]);                              \
          yB[j] = MFMA16(ub,        a2, yB[j]);                              \
        }                                                                    \
      }                                                                      \
      _Pragma("unroll")                                                      \
      for (int j = 0; j < 4; ++j)                                            \
        store_row4(f2[WR], nb[j], m,                                         \
                   fast_tanh(yA[j][0] + yB[j][0]),                           \
                   fast_tanh(yA[j][1] + yB[j][1]),                           \
                   fast_tanh(yA[j][2] + yB[j][2]),                           \
                   fast_tanh(yA[j][3] + yB[j][3]));                          \
    }                                                                        \
    block_sync_lds();                                                        \
  }

  // -------- main loop: 39 pairs cover i = 1..78; i = 79 peeled -------------
  for (int i = 1; i < TLEN - 1; i += 2) {
    int t2 = i + 3 < TLEN - 1 ? i + 3 : TLEN - 1;   // clamp (last pair only)
    RNN_STEP(0, 1, true, i + 2);    // i odd:  reads buf0, writes buf1
    RNN_STEP(1, 0, true, t2);       // i+1:    reads buf1, writes buf0
  }
  RNN_STEP(0, 1, false, TLEN - 1);  // i = 79: no prefetch (tkn load harmless)
#undef RNN_STEP

  // -------- tail (G1): h2[79] = tanh(b2 + h1[79]@W2 + h2[78]@U2) -> out ----
  if (!g0) {
    f32x4 yA[4], yB[4];
#pragma unroll
    for (int j = 0; j < 4; ++j) {
      yA[j] = b2v[j];
      yB[j] = (f32x4){0.f, 0.f, 0.f, 0.f};
    }
#pragma unroll
    for (int kt = 0; kt < 8; ++kt) {
      h8 a1 = *(const h8*)&f1[1][kt * 512 + lane * 8];   // h1[79]
      h8 a2 = *(const h8*)&f2[1][kt * 512 + lane * 8];   // h2[78]
#pragma unroll
      for (int j = 0; j < 4; ++j) {
        h8 ub = *(const h8*)&u2s[(((4 * wt + j) * 8 + kt) * 64 + lane) * 8];
        yA[j] = MFMA16(Bp[j][kt], a1, yA[j]);
        yB[j] = MFMA16(ub,        a2, yB[j]);
      }
    }
#pragma unroll
    for (int j = 0; j < 4; ++j) {
      f32x4 o;
#pragma unroll
      for (int r = 0; r < 4; ++r)
        o[r] = fast_sigmoid(fast_tanh(yA[j][r] + yB[j][r]));
      *(f32x4*)&out[(size_t)(b0 + m) * UNITS + nb[j]] = o;
    }
  }
}

// ---------------------------------------------------------------------------
extern "C" void kernel_launch(void* const* d_in, const int* in_sizes, int n_in,
                              void* d_out, int out_size, void* d_ws, size_t ws_size,
                              hipStream_t stream)
{
  const int*   idx = (const int*)d_in[0];
  const float* emb = (const float*)d_in[1];
  const float* W1  = (const float*)d_in[2];
  const float* U1  = (const float*)d_in[3];
  const float* b1  = (const float*)d_in[4];
  const float* W2  = (const float*)d_in[5];
  const float* U2  = (const float*)d_in[6];
  const float* b2  = (const float*)d_in[7];
  // d_in[8] (Wd), d_in[9] (bd) dead in the reference output.
  float* out = (float*)d_out;

  // 128 KB dynamic + 32 KB static = 160 KB LDS/workgroup (gfx950 max,
  // opt-in; AITER ships 160KB workgroups). 1 block/CU.
  static bool attr_done = false;
  if (!attr_done) {
    (void)hipFuncSetAttribute((const void*)rnn_wsH,
                              hipFuncAttributeMaxDynamicSharedMemorySize,
                              131072);
    attr_done = true;
  }

  f16* p1t = (f16*)((char*)d_ws + OFF_P1);
  f16* wf  = (f16*)((char*)d_ws + OFF_WF);
  k_p1<<<10000 / 16, 256, 0, stream>>>(emb, W1, b1, p1t);
  k_split_w16<<<(KT_ALL * 16 * 64 + 255) / 256, 256, 0, stream>>>(W1, U1, W2, U2, wf);
  rnn_wsH<<<BATCH / 16, 512, 131072, stream>>>(idx, p1t, wf, b2, out);
}

// Round 17
// 214.811 us; speedup vs baseline: 1.0600x; 1.0600x over previous
//
#include <hip/hip_runtime.h>

// Problem: VOCAB=10000, EMB=100, T=80, UNITS=256, BATCH=4096 — ALL FP32 I/O.
// out = sigmoid(h2_T);  h_l,t = tanh(x_l,t @ Wl + h_l,t-1 @ Ul + bl)
//
// v22 theory (from v21 regression + v20 counters): v21's role split doubled
// the U2 LDS stream and gated on G1 -> reverted. v20's real structure:
// MfmaUtil 41 + VALUBusy 47 ~= 88% — program order "48 MFMA then 16 tanh"
// makes MFMA phase (1860cy/SIMD) and VALU phase (~1800cy) SEQUENTIAL; both
// waves/SIMD in the same phase -> nothing hides. Fix: 4 sub-phases,
//   X (16 MFMA x-chains) ; TX (tanh x + f1 store + P1 prefetch) ;
//   Y (32 MFMA y-chains) ; TY (tanh y + f2 store) ; barrier
// -> the 2 waves/SIMD self-stagger (B stalls behind A in X, B's TX VALU
// runs under A's Y MFMAs). a1 re-read in Y (8 b128, ~100cy) instead of
// holding 32 regs across TX. Est 2600cy/iter vs 4180.
// Rest byte-identical to v20: swapped-operand MFMA, 160-reg "+v" pin
// (U1 a,b / W2 a,b / U2 a), u2b in 64KB dynamic LDS, lgkm-only barrier,
// register P1 gather prefetched one iter ahead, rcp-tanh, b64 frag writes.
// Tripwire: WRITE_SIZE must stay 4.1 MB.
#define BATCH 4096
#define TLEN  80
#define EMBD  100
#define UNITS 256

typedef _Float16 f16;
typedef __attribute__((ext_vector_type(8))) _Float16 h8;   // 8 f16 = 4 VGPR MFMA A/B frag
typedef __attribute__((ext_vector_type(4))) _Float16 h4;   // 4 f16 = b64
typedef __attribute__((ext_vector_type(4))) float f32x4;   // MFMA C/D frag

// tanh(x) = sign(x) * (1-e)/(1+e), e = exp(-2|x|) in (0,1].
__device__ __forceinline__ float fast_tanh(float x) {
  float ax = __builtin_fabsf(x);
  float e  = __expf(-2.f * ax);
  float r  = (1.f - e) * __builtin_amdgcn_rcpf(1.f + e);
  return __builtin_copysignf(r, x);
}
// sigmoid(x) = rcp(1 + exp(-x)); saturates correctly at both ends.
__device__ __forceinline__ float fast_sigmoid(float x) {
  return __builtin_amdgcn_rcpf(1.f + __expf(-x));
}

// LDS-only barrier: all prior LDS ops visible, but vmcnt NOT drained.
__device__ __forceinline__ void block_sync_lds() {
  asm volatile("s_waitcnt lgkmcnt(0)\n\ts_barrier" ::: "memory");
}

// ---------------- workspace layout (5.58 MB <= 6.04 MB proven available) ---
// P1 table: 10000 x 256 f16 = 5,120,000 B.  wf frags: 458,752 B.
// B-frag layout (16x16x32, r7-verified): lane holds B[k=quad*8+j][n=lane&15].
// ktg slots: W1 = 0..3 (unused by main), U1 = 4..11, W2 = 12..19, U2 = 20..27.
#define KT_ALL 28
#define OFF_P1 ((size_t)0)
#define P1_BYTES ((size_t)10000 * UNITS * 2)                // 5,120,000
#define OFF_WF  P1_BYTES
#define WF_BYTES ((size_t)KT_ALL * 16 * 64 * 8 * 2)         //   458,752
#define WS_NEED (OFF_WF + WF_BYTES)                          // 5,578,752 B

__device__ __forceinline__ size_t fidx(int ktg, int nt, int lane) {
  return (((size_t)ktg * 16 + nt) * 64 + lane) * 8;
}

// ---------------- precompute: weights -> swizzled fp16 B-frags (r10-verified)
__global__ __launch_bounds__(256) void k_split_w16(
    const float* __restrict__ W1, const float* __restrict__ U1,
    const float* __restrict__ W2, const float* __restrict__ U2,
    f16* __restrict__ wf)
{
  int gid = blockIdx.x * 256 + threadIdx.x;           // one per (ktg,nt,lane)
  if (gid >= KT_ALL * 16 * 64) return;
  int lane = gid & 63, nt = (gid >> 6) & 15, ktg = gid >> 10;
  const float* M; int Kact, ktl;
  if (ktg < 4)       { M = W1; Kact = EMBD;  ktl = ktg;      }
  else if (ktg < 12) { M = U1; Kact = UNITS; ktl = ktg - 4;  }
  else if (ktg < 20) { M = W2; Kact = UNITS; ktl = ktg - 12; }
  else               { M = U2; Kact = UNITS; ktl = ktg - 20; }
  int n = nt * 16 + (lane & 15);
  int kb = ktl * 32 + (lane >> 4) * 8;
  size_t base = fidx(ktg, nt, lane);
#pragma unroll
  for (int j = 0; j < 8; ++j) {
    int k = kb + j;
    wf[base + j] = (f16)((k < Kact) ? M[(size_t)k * UNITS + n] : 0.f);  // RNE
  }
}

// ---------------- precompute: P1[v][n] = b1[n] + emb[v,:] @ W1 (f32 math) --
__global__ __launch_bounds__(256) void k_p1(
    const float* __restrict__ emb, const float* __restrict__ W1,
    const float* __restrict__ b1, f16* __restrict__ p1t)
{
  __shared__ float er[16][EMBD];
  const int v0 = blockIdx.x * 16;
  for (int i = threadIdx.x; i < 16 * EMBD; i += 256) {
    int vv = i / EMBD, kk = i - vv * EMBD;
    er[vv][kk] = emb[(size_t)(v0 + vv) * EMBD + kk];
  }
  __syncthreads();
  const int n = threadIdx.x;
  float acc[16];
  const float bb = b1[n];
#pragma unroll
  for (int vv = 0; vv < 16; ++vv) acc[vv] = bb;
  for (int k = 0; k < EMBD; ++k) {
    float w = W1[(size_t)k * UNITS + n];
#pragma unroll
    for (int vv = 0; vv < 16; ++vv) acc[vv] += er[vv][k] * w;
  }
#pragma unroll
  for (int vv = 0; vv < 16; ++vv)
    p1t[(size_t)(v0 + vv) * UNITS + n] = (f16)acc[vv];
}

#define MFMA16(A, B, C) __builtin_amdgcn_mfma_f32_16x16x32_f16(A, B, C, 0, 0, 0)

// store 4 consecutive-n f16 of the next-step A-frag in ONE b64 write.
// A-frag element (batch=m, k=n) lives at (n>>5)*512 + (((n>>3)&3)*16+m)*8
// + (n&7); for nb multiple of 4, the 4 targets are consecutive (8B-aligned).
__device__ __forceinline__ void store_row4(f16* __restrict__ f, int nb, int m,
                                           float v0, float v1, float v2, float v3) {
  int a = (nb >> 5) * 512 + (((nb >> 3) & 3) * 16 + m) * 8 + (nb & 7);
  h4 p; p[0] = (f16)v0; p[1] = (f16)v1; p[2] = (f16)v2; p[3] = (f16)v3;
  *(h4*)&f[a] = p;
}

// ---------------------------------------------------------------------------
// Main kernel v22: 512 thr = 8 waves (2/SIMD), wave w owns n-tiles 2w, 2w+1.
// SWAPPED-OPERAND MFMA: D = MFMA(Wfrag, hfrag) = (h@W)^T; lane holds
// (n = tilebase + q*4 + r, batch = m). Iter i computes h1[i] and h2[i-1]
// in 4 sub-phases (X / TX / Y / TY) for cross-wave MFMA-VALU overlap;
// one lgkm-only barrier/iter; compile-time buffer indices.
// Pinned: U1(a,b) W2(a,b) U2(a) = 160 regs.  U2(b): 64 KB dynamic LDS.
// P1: 2 x b64 register gather per lane, prefetched one iter ahead (no LDS).
// ---------------------------------------------------------------------------
__global__ __launch_bounds__(512, 2)
__attribute__((amdgpu_waves_per_eu(2, 2)))
void rnn_wsI(
    const int* __restrict__ idx, const f16* __restrict__ p1t,
    const f16* __restrict__ wf, const float* __restrict__ b2,
    float* __restrict__ out)
{
  __shared__ __align__(16) f16 f1[2][4096];      // [buf][kt*512 + lane*8 + j]
  __shared__ __align__(16) f16 f2[2][4096];
  extern __shared__ f16 u2s[];                   // 64 KB: odd tiles of U2

  const int tid  = threadIdx.x;
  const int lane = tid & 63;
  const int w    = tid >> 6;          // wave 0..7 -> n-tiles 2w, 2w+1
  const int m    = lane & 15;         // batch row this lane accumulates
  const int q    = lane >> 4;
  const int b0   = blockIdx.x * 16;
  const int n0b  = 32 * w + 4 * q;    // 4-col group base, tile 2w
  const int n1b  = n0b + 16;          // tile 2w+1

  // bias: 4 consecutive n per tile (16B-aligned)
  const f32x4 b2v0 = *(const f32x4*)&b2[n0b];
  const f32x4 b2v1 = *(const f32x4*)&b2[n1b];

  // per-lane token pointer (row m) and hoisted P1 gather base
  const int* tokm = idx + (size_t)(b0 + m) * TLEN;
  const f16* __restrict__ p1g = p1t + n0b;       // +tok*UNITS, +16 for n1b

  // -------- stage U2 odd tiles into LDS (64 KB / 512 thr = 8 h8 each) -----
  for (int d = tid; d < 4096; d += 512) {        // d = (no*8+kt)*64 + l
    int l = d & 63, g = d >> 6, no = g >> 3, kt = g & 7;
    *(h8*)&u2s[(size_t)d * 8] = *(const h8*)(wf + fidx(20 + kt, 2 * no + 1, l));
  }

  // -------- persistent weight fragments: U1(a,b), W2(a,b), U2(a) -----------
  // (bytes unchanged: a W B-frag IS the A-frag of W^T)
  h8 Bu1a[8], Bu1b[8], Bw2a[8], Bw2b[8], Bu2a[8];
#pragma unroll
  for (int kt = 0; kt < 8; ++kt) {
    Bu1a[kt] = *(const h8*)(wf + fidx(4 + kt, 2 * w, lane));
    Bu1b[kt] = *(const h8*)(wf + fidx(4 + kt, 2 * w + 1, lane));
    Bw2a[kt] = *(const h8*)(wf + fidx(12 + kt, 2 * w, lane));
    Bw2b[kt] = *(const h8*)(wf + fidx(12 + kt, 2 * w + 1, lane));
    Bu2a[kt] = *(const h8*)(wf + fidx(20 + kt, 2 * w, lane));
  }
  // pin ("+v", proven spill-free at exactly this 160-reg footprint)
#pragma unroll
  for (int kt = 0; kt < 8; ++kt) {
    asm volatile("" : "+v"(Bu1a[kt])); asm volatile("" : "+v"(Bu1b[kt]));
    asm volatile("" : "+v"(Bw2a[kt])); asm volatile("" : "+v"(Bw2b[kt]));
    asm volatile("" : "+v"(Bu2a[kt]));
  }

  // -------- zero h2[-1] state (f2[0]); f1[0] fully written by the peel -----
  for (int i = tid; i < 4096; i += 512) f2[0][i] = (f16)0.f;

  // -------- peel i=0: h1[0] = tanh(P1[0]) — b64 gather, b64 frag write -----
  {
    const f16* pr = p1g + (size_t)tokm[0] * UNITS;
    h4 v0 = *(const h4*)(pr);
    h4 v1 = *(const h4*)(pr + 16);
    store_row4(f1[0], n0b, m, fast_tanh((float)v0[0]), fast_tanh((float)v0[1]),
                              fast_tanh((float)v0[2]), fast_tanh((float)v0[3]));
    store_row4(f1[0], n1b, m, fast_tanh((float)v1[0]), fast_tanh((float)v1[1]),
                              fast_tanh((float)v1[2]), fast_tanh((float)v1[3]));
  }

  // -------- prime the P1 register pipeline: pv = P1[1], tkn = tok[2] -------
  h4 pv0, pv1;
  {
    const f16* pr = p1g + (size_t)tokm[1] * UNITS;
    pv0 = *(const h4*)(pr);
    pv1 = *(const h4*)(pr + 16);
  }
  int tkn = tokm[2];                   // token for iter1's prefetch of P1[2]
  __syncthreads();   // full barrier once: u2s, f2 zero, peel

  // ======== one pipelined step; RD/WR are COMPILE-TIME 0/1 =================
  // 4 sub-phases: X (x-chains) / TX (tanh x + f1 store + P1 prefetch) /
  // Y (y-chains) / TY (tanh y + f2 store). Waves self-stagger: one wave's
  // TX/TY VALU hides under the other's X/Y MFMA pipe occupancy.
#define RNN_STEP(RD, WR, STAGE, TKI)                                         \
  {                                                                          \
    /* ---- X: layer-1 chains (16 MFMA; reads a1 only) ---- */               \
    f32x4 x0, x1;                                                            \
    _Pragma("unroll")                                                        \
    for (int r = 0; r < 4; ++r) {                                            \
      x0[r] = (float)pv0[r];                                                 \
      x1[r] = (float)pv1[r];                                                 \
    }                                                                        \
    _Pragma("unroll")                                                        \
    for (int kt = 0; kt < 8; ++kt) {                                         \
      h8 a1 = *(const h8*)&f1[RD][kt * 512 + lane * 8];                      \
      x0 = MFMA16(Bu1a[kt], a1, x0);                                         \
      x1 = MFMA16(Bu1b[kt], a1, x1);                                         \
    }                                                                        \
    /* ---- TX: P1 prefetch issue + tanh(x) + f1[WR] store ---- */           \
    if (STAGE) {                                                             \
      const f16* pr_ = p1g + (size_t)tkn * UNITS;                            \
      pv0 = *(const h4*)(pr_);                                               \
      pv1 = *(const h4*)(pr_ + 16);                                          \
    }                                                                        \
    tkn = tokm[TKI];                                                         \
    store_row4(f1[WR], n0b, m, fast_tanh(x0[0]), fast_tanh(x0[1]),           \
                               fast_tanh(x0[2]), fast_tanh(x0[3]));          \
    store_row4(f1[WR], n1b, m, fast_tanh(x1[0]), fast_tanh(x1[1]),           \
                               fast_tanh(x1[2]), fast_tanh(x1[3]));          \
    /* ---- Y: layer-2 chains (32 MFMA; re-reads a1, reads a2+ub) ---- */    \
    f32x4 yA0 = b2v0, yA1 = b2v1;                                            \
    f32x4 yB0 = (f32x4){0.f, 0.f, 0.f, 0.f};                                 \
    f32x4 yB1 = (f32x4){0.f, 0.f, 0.f, 0.f};                                 \
    _Pragma("unroll")                                                        \
    for (int kt = 0; kt < 8; ++kt) {                                         \
      h8 a1 = *(const h8*)&f1[RD][kt * 512 + lane * 8];                      \
      h8 a2 = *(const h8*)&f2[RD][kt * 512 + lane * 8];                      \
      h8 ub = *(const h8*)&u2s[((w * 8 + kt) * 64 + lane) * 8];              \
      yA0 = MFMA16(Bw2a[kt], a1, yA0);                                       \
      yA1 = MFMA16(Bw2b[kt], a1, yA1);                                       \
      yB0 = MFMA16(Bu2a[kt], a2, yB0);                                       \
      yB1 = MFMA16(ub,       a2, yB1);                                       \
    }                                                                        \
    /* ---- TY: tanh(y) + f2[WR] store ---- */                               \
    store_row4(f2[WR], n0b, m,                                               \
               fast_tanh(yA0[0] + yB0[0]), fast_tanh(yA0[1] + yB0[1]),       \
               fast_tanh(yA0[2] + yB0[2]), fast_tanh(yA0[3] + yB0[3]));      \
    store_row4(f2[WR], n1b, m,                                               \
               fast_tanh(yA1[0] + yB1[0]), fast_tanh(yA1[1] + yB1[1]),       \
               fast_tanh(yA1[2] + yB1[2]), fast_tanh(yA1[3] + yB1[3]));      \
    block_sync_lds();                                                        \
  }

  // -------- main loop: 39 pairs cover i = 1..78; i = 79 peeled -------------
  for (int i = 1; i < TLEN - 1; i += 2) {
    int t2 = i + 3 < TLEN - 1 ? i + 3 : TLEN - 1;   // clamp (last pair only)
    RNN_STEP(0, 1, true, i + 2);    // i odd:  reads buf0, writes buf1
    RNN_STEP(1, 0, true, t2);       // i+1:    reads buf1, writes buf0
  }
  RNN_STEP(0, 1, false, TLEN - 1);  // i = 79: no prefetch (tkn load harmless)
#undef RNN_STEP

  // -------- tail: h2[79] = tanh(b2 + h1[79]@W2 + h2[78]@U2) -> out ---------
  {
    f32x4 yA0 = b2v0, yA1 = b2v1;
    f32x4 yB0 = (f32x4){0.f, 0.f, 0.f, 0.f};
    f32x4 yB1 = (f32x4){0.f, 0.f, 0.f, 0.f};
#pragma unroll
    for (int kt = 0; kt < 8; ++kt) {
      h8 a1 = *(const h8*)&f1[1][kt * 512 + lane * 8];   // h1[79]
      h8 a2 = *(const h8*)&f2[1][kt * 512 + lane * 8];   // h2[78]
      h8 ub = *(const h8*)&u2s[((w * 8 + kt) * 64 + lane) * 8];
      yA0 = MFMA16(Bw2a[kt], a1, yA0);
      yA1 = MFMA16(Bw2b[kt], a1, yA1);
      yB0 = MFMA16(Bu2a[kt], a2, yB0);
      yB1 = MFMA16(ub,       a2, yB1);
    }
    f32x4 o0, o1;
#pragma unroll
    for (int r = 0; r < 4; ++r) {
      o0[r] = fast_sigmoid(fast_tanh(yA0[r] + yB0[r]));
      o1[r] = fast_sigmoid(fast_tanh(yA1[r] + yB1[r]));
    }
    *(f32x4*)&out[(size_t)(b0 + m) * UNITS + n0b] = o0;
    *(f32x4*)&out[(size_t)(b0 + m) * UNITS + n1b] = o1;
  }
}

// ---------------------------------------------------------------------------
extern "C" void kernel_launch(void* const* d_in, const int* in_sizes, int n_in,
                              void* d_out, int out_size, void* d_ws, size_t ws_size,
                              hipStream_t stream)
{
  const int*   idx = (const int*)d_in[0];
  const float* emb = (const float*)d_in[1];
  const float* W1  = (const float*)d_in[2];
  const float* U1  = (const float*)d_in[3];
  const float* b1  = (const float*)d_in[4];
  const float* W2  = (const float*)d_in[5];
  const float* U2  = (const float*)d_in[6];
  const float* b2  = (const float*)d_in[7];
  // d_in[8] (Wd), d_in[9] (bd) dead in the reference output.
  float* out = (float*)d_out;

  // 64 KB dynamic + 32 KB static = 96 KB LDS/workgroup -> 1 block/CU.
  static bool attr_done = false;
  if (!attr_done) {
    (void)hipFuncSetAttribute((const void*)rnn_wsI,
                              hipFuncAttributeMaxDynamicSharedMemorySize,
                              65536);
    attr_done = true;
  }

  f16* p1t = (f16*)((char*)d_ws + OFF_P1);
  f16* wf  = (f16*)((char*)d_ws + OFF_WF);
  k_p1<<<10000 / 16, 256, 0, stream>>>(emb, W1, b1, p1t);
  k_split_w16<<<(KT_ALL * 16 * 64 + 255) / 256, 256, 0, stream>>>(W1, U1, W2, U2, wf);
  rnn_wsI<<<BATCH / 16, 512, 65536, stream>>>(idx, p1t, wf, b2, out);
}

// Round 18
// 204.832 us; speedup vs baseline: 1.1116x; 1.0487x over previous
//
#include <hip/hip_runtime.h>

// Problem: VOCAB=10000, EMB=100, T=80, UNITS=256, BATCH=4096 — ALL FP32 I/O.
// out = sigmoid(h2_T);  h_l,t = tanh(x_l,t @ Wl + h_l,t-1 @ Ul + bl)
//
// v23 theory (from v22 counters): phase reorder regressed (146.5 vs 139.3)
// -> revert to v20's rnn kernel (verified best). New lever: the GRADED
// dur_us = rnn dispatch + ~75us fixed cost, and the gap grew ~35us when
// k_p1 appeared (v9): k_p1 does 100x16 scalar LDS reads PER THREAD
// (~10^7 ds_read_b32 across 625 blocks) — a ~35us precompute. Rebuild it
// with MFMA using the W1 B-frags ALREADY in wf (ktg 0..3, zero-padded
// K=128, unused since v9): per block 16 vocab rows, 4 waves x 4 n-tiles,
// emb A-frag gathered once (L3-resident), 16 swapped-operand MFMAs/wave,
// acc init = b1, b64 stores. Est ~4us. Numerics: adds only emb->f16
// rounding (~100x below existing f16 state rounding).
// Main kernel: v20 byte-identical (swapped-operand MFMA, 160-reg "+v" pin,
// u2b in 64KB dynamic LDS, lgkm-only barrier, register P1 gather).
// Tripwire: WRITE_SIZE must stay 4.1 MB; absmax must stay 0.0039.
#define BATCH 4096
#define TLEN  80
#define EMBD  100
#define UNITS 256

typedef _Float16 f16;
typedef __attribute__((ext_vector_type(8))) _Float16 h8;   // 8 f16 = 4 VGPR MFMA A/B frag
typedef __attribute__((ext_vector_type(4))) _Float16 h4;   // 4 f16 = b64
typedef __attribute__((ext_vector_type(4))) float f32x4;   // MFMA C/D frag

// tanh(x) = sign(x) * (1-e)/(1+e), e = exp(-2|x|) in (0,1].
__device__ __forceinline__ float fast_tanh(float x) {
  float ax = __builtin_fabsf(x);
  float e  = __expf(-2.f * ax);
  float r  = (1.f - e) * __builtin_amdgcn_rcpf(1.f + e);
  return __builtin_copysignf(r, x);
}
// sigmoid(x) = rcp(1 + exp(-x)); saturates correctly at both ends.
__device__ __forceinline__ float fast_sigmoid(float x) {
  return __builtin_amdgcn_rcpf(1.f + __expf(-x));
}

// LDS-only barrier: all prior LDS ops visible, but vmcnt NOT drained.
__device__ __forceinline__ void block_sync_lds() {
  asm volatile("s_waitcnt lgkmcnt(0)\n\ts_barrier" ::: "memory");
}

// ---------------- workspace layout (5.58 MB <= 6.04 MB proven available) ---
// P1 table: 10000 x 256 f16 = 5,120,000 B.  wf frags: 458,752 B.
// B-frag layout (16x16x32, r7-verified): lane holds B[k=quad*8+j][n=lane&15].
// ktg slots: W1 = 0..3 (used by k_p1m), U1 = 4..11, W2 = 12..19, U2 = 20..27.
#define KT_ALL 28
#define OFF_P1 ((size_t)0)
#define P1_BYTES ((size_t)10000 * UNITS * 2)                // 5,120,000
#define OFF_WF  P1_BYTES
#define WF_BYTES ((size_t)KT_ALL * 16 * 64 * 8 * 2)         //   458,752
#define WS_NEED (OFF_WF + WF_BYTES)                          // 5,578,752 B

__device__ __forceinline__ size_t fidx(int ktg, int nt, int lane) {
  return (((size_t)ktg * 16 + nt) * 64 + lane) * 8;
}

// ---------------- precompute: weights -> swizzled fp16 B-frags (r10-verified)
__global__ __launch_bounds__(256) void k_split_w16(
    const float* __restrict__ W1, const float* __restrict__ U1,
    const float* __restrict__ W2, const float* __restrict__ U2,
    f16* __restrict__ wf)
{
  int gid = blockIdx.x * 256 + threadIdx.x;           // one per (ktg,nt,lane)
  if (gid >= KT_ALL * 16 * 64) return;
  int lane = gid & 63, nt = (gid >> 6) & 15, ktg = gid >> 10;
  const float* M; int Kact, ktl;
  if (ktg < 4)       { M = W1; Kact = EMBD;  ktl = ktg;      }
  else if (ktg < 12) { M = U1; Kact = UNITS; ktl = ktg - 4;  }
  else if (ktg < 20) { M = W2; Kact = UNITS; ktl = ktg - 12; }
  else               { M = U2; Kact = UNITS; ktl = ktg - 20; }
  int n = nt * 16 + (lane & 15);
  int kb = ktl * 32 + (lane >> 4) * 8;
  size_t base = fidx(ktg, nt, lane);
#pragma unroll
  for (int j = 0; j < 8; ++j) {
    int k = kb + j;
    wf[base + j] = (f16)((k < Kact) ? M[(size_t)k * UNITS + n] : 0.f);  // RNE
  }
}

#define MFMA16(A, B, C) __builtin_amdgcn_mfma_f32_16x16x32_f16(A, B, C, 0, 0, 0)

// ---------------- precompute v23: P1 = b1 + emb@W1 via MFMA ----------------
// 625 blocks x 256 thr (4 waves); wave w owns n-tiles 4w..4w+3; block covers
// 16 vocab rows. A-frag of emb gathered as f16 (K padded to 128); W1 B-frags
// come from wf ktg 0..3 (already zero-padded). Swapped-operand MFMA =>
// lane holds (4 consecutive n, vocab row m): b64 stores.
__global__ __launch_bounds__(256) void k_p1m(
    const float* __restrict__ emb, const f16* __restrict__ wf,
    const float* __restrict__ b1, f16* __restrict__ p1t)
{
  const int lane = threadIdx.x & 63;
  const int w    = threadIdx.x >> 6;     // 0..3 -> n-tiles 4w..4w+3
  const int m    = lane & 15;
  const int q    = lane >> 4;
  const int row  = blockIdx.x * 16 + m;  // vocab row

  // A-frag: lane (q,m) holds emb[row][k], k = kt*32 + q*8 + j (0 if k>=100)
  h8 ae[4];
  const float* er = emb + (size_t)row * EMBD;
#pragma unroll
  for (int kt = 0; kt < 4; ++kt)
#pragma unroll
    for (int j = 0; j < 8; ++j) {
      int k = kt * 32 + q * 8 + j;
      ae[kt][j] = (f16)((k < EMBD) ? er[k] : 0.f);
    }

#pragma unroll
  for (int j = 0; j < 4; ++j) {
    int nt = 4 * w + j;
    int nb = nt * 16 + 4 * q;
    f32x4 acc = *(const f32x4*)&b1[nb];          // b1 folded in (16B-aligned)
#pragma unroll
    for (int kt = 0; kt < 4; ++kt) {
      h8 bw = *(const h8*)(wf + fidx(kt, nt, lane));
      acc = MFMA16(bw, ae[kt], acc);             // (emb@W1)^T fragment
    }
    h4 p;
#pragma unroll
    for (int r = 0; r < 4; ++r) p[r] = (f16)acc[r];
    *(h4*)&p1t[(size_t)row * UNITS + nb] = p;
  }
}

// store 4 consecutive-n f16 of the next-step A-frag in ONE b64 write.
// A-frag element (batch=m, k=n) lives at (n>>5)*512 + (((n>>3)&3)*16+m)*8
// + (n&7); for nb multiple of 4, the 4 targets are consecutive (8B-aligned).
__device__ __forceinline__ void store_row4(f16* __restrict__ f, int nb, int m,
                                           float v0, float v1, float v2, float v3) {
  int a = (nb >> 5) * 512 + (((nb >> 3) & 3) * 16 + m) * 8 + (nb & 7);
  h4 p; p[0] = (f16)v0; p[1] = (f16)v1; p[2] = (f16)v2; p[3] = (f16)v3;
  *(h4*)&f[a] = p;
}

// ---------------------------------------------------------------------------
// Main kernel v23 (= v20): 512 thr = 8 waves (2/SIMD), wave w owns n-tiles
// 2w, 2w+1. SWAPPED-OPERAND MFMA: D = MFMA(Wfrag, hfrag) = (h@W)^T; lane
// holds (n = tilebase + q*4 + r, batch = m). Iter i computes h1[i], h2[i-1];
// one lgkm-only barrier/iter; compile-time buffer indices.
// Pinned: U1(a,b) W2(a,b) U2(a) = 160 regs.  U2(b): 64 KB dynamic LDS.
// P1: 2 x b64 register gather per lane, prefetched one iter ahead (no LDS).
// ---------------------------------------------------------------------------
__global__ __launch_bounds__(512, 2)
__attribute__((amdgpu_waves_per_eu(2, 2)))
void rnn_wsG(
    const int* __restrict__ idx, const f16* __restrict__ p1t,
    const f16* __restrict__ wf, const float* __restrict__ b2,
    float* __restrict__ out)
{
  __shared__ __align__(16) f16 f1[2][4096];      // [buf][kt*512 + lane*8 + j]
  __shared__ __align__(16) f16 f2[2][4096];
  extern __shared__ f16 u2s[];                   // 64 KB: odd tiles of U2

  const int tid  = threadIdx.x;
  const int lane = tid & 63;
  const int w    = tid >> 6;          // wave 0..7 -> n-tiles 2w, 2w+1
  const int m    = lane & 15;         // batch row this lane accumulates
  const int q    = lane >> 4;
  const int b0   = blockIdx.x * 16;
  const int n0b  = 32 * w + 4 * q;    // 4-col group base, tile 2w
  const int n1b  = n0b + 16;          // tile 2w+1

  // bias: 4 consecutive n per tile (16B-aligned)
  const f32x4 b2v0 = *(const f32x4*)&b2[n0b];
  const f32x4 b2v1 = *(const f32x4*)&b2[n1b];

  // per-lane token pointer (row m) and hoisted P1 gather base
  const int* tokm = idx + (size_t)(b0 + m) * TLEN;
  const f16* __restrict__ p1g = p1t + n0b;       // +tok*UNITS, +16 for n1b

  // -------- stage U2 odd tiles into LDS (64 KB / 512 thr = 8 h8 each) -----
  for (int d = tid; d < 4096; d += 512) {        // d = (no*8+kt)*64 + l
    int l = d & 63, g = d >> 6, no = g >> 3, kt = g & 7;
    *(h8*)&u2s[(size_t)d * 8] = *(const h8*)(wf + fidx(20 + kt, 2 * no + 1, l));
  }

  // -------- persistent weight fragments: U1(a,b), W2(a,b), U2(a) -----------
  // (bytes unchanged: a W B-frag IS the A-frag of W^T)
  h8 Bu1a[8], Bu1b[8], Bw2a[8], Bw2b[8], Bu2a[8];
#pragma unroll
  for (int kt = 0; kt < 8; ++kt) {
    Bu1a[kt] = *(const h8*)(wf + fidx(4 + kt, 2 * w, lane));
    Bu1b[kt] = *(const h8*)(wf + fidx(4 + kt, 2 * w + 1, lane));
    Bw2a[kt] = *(const h8*)(wf + fidx(12 + kt, 2 * w, lane));
    Bw2b[kt] = *(const h8*)(wf + fidx(12 + kt, 2 * w + 1, lane));
    Bu2a[kt] = *(const h8*)(wf + fidx(20 + kt, 2 * w, lane));
  }
  // pin ("+v", proven spill-free at exactly this 160-reg footprint)
#pragma unroll
  for (int kt = 0; kt < 8; ++kt) {
    asm volatile("" : "+v"(Bu1a[kt])); asm volatile("" : "+v"(Bu1b[kt]));
    asm volatile("" : "+v"(Bw2a[kt])); asm volatile("" : "+v"(Bw2b[kt]));
    asm volatile("" : "+v"(Bu2a[kt]));
  }

  // -------- zero h2[-1] state (f2[0]); f1[0] fully written by the peel -----
  for (int i = tid; i < 4096; i += 512) f2[0][i] = (f16)0.f;

  // -------- peel i=0: h1[0] = tanh(P1[0]) — b64 gather, b64 frag write -----
  {
    const f16* pr = p1g + (size_t)tokm[0] * UNITS;
    h4 v0 = *(const h4*)(pr);
    h4 v1 = *(const h4*)(pr + 16);
    store_row4(f1[0], n0b, m, fast_tanh((float)v0[0]), fast_tanh((float)v0[1]),
                              fast_tanh((float)v0[2]), fast_tanh((float)v0[3]));
    store_row4(f1[0], n1b, m, fast_tanh((float)v1[0]), fast_tanh((float)v1[1]),
                              fast_tanh((float)v1[2]), fast_tanh((float)v1[3]));
  }

  // -------- prime the P1 register pipeline: pv = P1[1], tkn = tok[2] -------
  h4 pv0, pv1;
  {
    const f16* pr = p1g + (size_t)tokm[1] * UNITS;
    pv0 = *(const h4*)(pr);
    pv1 = *(const h4*)(pr + 16);
  }
  int tkn = tokm[2];                   // token for iter1's prefetch of P1[2]
  __syncthreads();   // full barrier once: u2s, f2 zero, peel

  // ======== one pipelined step; RD/WR are COMPILE-TIME 0/1 =================
  // Reads f1[RD], f2[RD]; writes f1[WR], f2[WR]. P1 flows through pv0/pv1
  // registers: consume (acc init) -> immediately issue next gather -> the
  // MFMA section hides its L2 latency; lgkm barrier leaves it in flight.
#define RNN_STEP(RD, WR, STAGE, TKI)                                         \
  {                                                                          \
    f32x4 x0, x1;                                                            \
    _Pragma("unroll")                                                        \
    for (int r = 0; r < 4; ++r) {                                            \
      x0[r] = (float)pv0[r];                                                 \
      x1[r] = (float)pv1[r];                                                 \
    }                                                                        \
    if (STAGE) {                                                             \
      const f16* pr_ = p1g + (size_t)tkn * UNITS;                            \
      pv0 = *(const h4*)(pr_);                                               \
      pv1 = *(const h4*)(pr_ + 16);                                          \
    }                                                                        \
    tkn = tokm[TKI];                                                         \
    f32x4 yA0 = b2v0, yA1 = b2v1;                                            \
    f32x4 yB0 = (f32x4){0.f, 0.f, 0.f, 0.f};                                 \
    f32x4 yB1 = (f32x4){0.f, 0.f, 0.f, 0.f};                                 \
    _Pragma("unroll")                                                        \
    for (int kt = 0; kt < 8; ++kt) {                                         \
      h8 a1 = *(const h8*)&f1[RD][kt * 512 + lane * 8];                      \
      h8 a2 = *(const h8*)&f2[RD][kt * 512 + lane * 8];                      \
      h8 ub = *(const h8*)&u2s[((w * 8 + kt) * 64 + lane) * 8];              \
      x0  = MFMA16(Bu1a[kt], a1, x0);                                        \
      x1  = MFMA16(Bu1b[kt], a1, x1);                                        \
      yA0 = MFMA16(Bw2a[kt], a1, yA0);                                       \
      yA1 = MFMA16(Bw2b[kt], a1, yA1);                                       \
      yB0 = MFMA16(Bu2a[kt], a2, yB0);                                       \
      yB1 = MFMA16(ub,       a2, yB1);                                       \
    }                                                                        \
    store_row4(f1[WR], n0b, m, fast_tanh(x0[0]), fast_tanh(x0[1]),           \
                               fast_tanh(x0[2]), fast_tanh(x0[3]));          \
    store_row4(f1[WR], n1b, m, fast_tanh(x1[0]), fast_tanh(x1[1]),           \
                               fast_tanh(x1[2]), fast_tanh(x1[3]));          \
    store_row4(f2[WR], n0b, m,                                               \
               fast_tanh(yA0[0] + yB0[0]), fast_tanh(yA0[1] + yB0[1]),       \
               fast_tanh(yA0[2] + yB0[2]), fast_tanh(yA0[3] + yB0[3]));      \
    store_row4(f2[WR], n1b, m,                                               \
               fast_tanh(yA1[0] + yB1[0]), fast_tanh(yA1[1] + yB1[1]),       \
               fast_tanh(yA1[2] + yB1[2]), fast_tanh(yA1[3] + yB1[3]));      \
    block_sync_lds();                                                        \
  }

  // -------- main loop: 39 pairs cover i = 1..78; i = 79 peeled -------------
  for (int i = 1; i < TLEN - 1; i += 2) {
    int t2 = i + 3 < TLEN - 1 ? i + 3 : TLEN - 1;   // clamp (last pair only)
    RNN_STEP(0, 1, true, i + 2);    // i odd:  reads buf0, writes buf1
    RNN_STEP(1, 0, true, t2);       // i+1:    reads buf1, writes buf0
  }
  RNN_STEP(0, 1, false, TLEN - 1);  // i = 79: no prefetch (tkn load harmless)
#undef RNN_STEP

  // -------- tail: h2[79] = tanh(b2 + h1[79]@W2 + h2[78]@U2) -> out ---------
  {
    f32x4 yA0 = b2v0, yA1 = b2v1;
    f32x4 yB0 = (f32x4){0.f, 0.f, 0.f, 0.f};
    f32x4 yB1 = (f32x4){0.f, 0.f, 0.f, 0.f};
#pragma unroll
    for (int kt = 0; kt < 8; ++kt) {
      h8 a1 = *(const h8*)&f1[1][kt * 512 + lane * 8];   // h1[79]
      h8 a2 = *(const h8*)&f2[1][kt * 512 + lane * 8];   // h2[78]
      h8 ub = *(const h8*)&u2s[((w * 8 + kt) * 64 + lane) * 8];
      yA0 = MFMA16(Bw2a[kt], a1, yA0);
      yA1 = MFMA16(Bw2b[kt], a1, yA1);
      yB0 = MFMA16(Bu2a[kt], a2, yB0);
      yB1 = MFMA16(ub,       a2, yB1);
    }
    f32x4 o0, o1;
#pragma unroll
    for (int r = 0; r < 4; ++r) {
      o0[r] = fast_sigmoid(fast_tanh(yA0[r] + yB0[r]));
      o1[r] = fast_sigmoid(fast_tanh(yA1[r] + yB1[r]));
    }
    *(f32x4*)&out[(size_t)(b0 + m) * UNITS + n0b] = o0;
    *(f32x4*)&out[(size_t)(b0 + m) * UNITS + n1b] = o1;
  }
}

// ---------------------------------------------------------------------------
extern "C" void kernel_launch(void* const* d_in, const int* in_sizes, int n_in,
                              void* d_out, int out_size, void* d_ws, size_t ws_size,
                              hipStream_t stream)
{
  const int*   idx = (const int*)d_in[0];
  const float* emb = (const float*)d_in[1];
  const float* W1  = (const float*)d_in[2];
  const float* U1  = (const float*)d_in[3];
  const float* b1  = (const float*)d_in[4];
  const float* W2  = (const float*)d_in[5];
  const float* U2  = (const float*)d_in[6];
  const float* b2  = (const float*)d_in[7];
  // d_in[8] (Wd), d_in[9] (bd) dead in the reference output.
  float* out = (float*)d_out;

  // 64 KB dynamic + 32 KB static = 96 KB LDS/workgroup -> 1 block/CU.
  static bool attr_done = false;
  if (!attr_done) {
    (void)hipFuncSetAttribute((const void*)rnn_wsG,
                              hipFuncAttributeMaxDynamicSharedMemorySize,
                              65536);
    attr_done = true;
  }

  f16* p1t = (f16*)((char*)d_ws + OFF_P1);
  f16* wf  = (f16*)((char*)d_ws + OFF_WF);
  // order matters: k_p1m consumes wf (W1 frags, ktg 0..3)
  k_split_w16<<<(KT_ALL * 16 * 64 + 255) / 256, 256, 0, stream>>>(W1, U1, W2, U2, wf);
  k_p1m<<<10000 / 16, 256, 0, stream>>>(emb, wf, b1, p1t);
  rnn_wsG<<<BATCH / 16, 512, 65536, stream>>>(idx, p1t, wf, b2, out);
}